// Round 1
// baseline (755.351 us; speedup 1.0000x reference)
//
#include <hip/hip_runtime.h>

// Problem constants (fixed by the reference).
static constexpr int N_ = 1024;
static constexpr int S_ = 144;
static constexpr int R_ = 96;
static constexpr int K_ = 128;
static constexpr int D_ = 768;

typedef __attribute__((ext_vector_type(8))) short short8;   // 8 bf16 = 4 VGPR
typedef __attribute__((ext_vector_type(4))) short short4_t; // 4 bf16 = 8 B
typedef __attribute__((ext_vector_type(4))) float floatx4;  // MFMA acc

__device__ inline short f2bf(float f) {  // fp32 -> bf16 RNE
  unsigned u = __builtin_bit_cast(unsigned, f);
  return (short)((u + 0x7FFFu + ((u >> 16) & 1u)) >> 16);
}

// Async global->LDS, 16 B per lane. LDS dest is wave-uniform base; HW adds
// lane*16. Fallback path does the equivalent register round-trip.
#if defined(__has_builtin)
#if __has_builtin(__builtin_amdgcn_global_load_lds)
#define HAS_GLL 1
#endif
#endif
#ifndef HAS_GLL
#define HAS_GLL 0
#endif

__device__ __forceinline__ void stage16(const void* g, void* lds_base, int lane) {
#if HAS_GLL
  __builtin_amdgcn_global_load_lds(
      (const __attribute__((address_space(1))) void*)g,
      (__attribute__((address_space(3))) void*)lds_base, 16, 0, 0);
#else
  *(short8*)((short*)lds_base + lane * 8) = *(const short8*)g;
#endif
}

// ---------------------------------------------------------------------------
// ragged lambdas -> dense (R,K) fp32 with 0 padding.
// ---------------------------------------------------------------------------
__global__ __launch_bounds__(256) void k_pad_lambdas(
    const float* __restrict__ lambdas, const int* __restrict__ lens,
    float* __restrict__ ul) {
  __shared__ int offs[R_];
  if (threadIdx.x == 0) {
    int acc = 0;
    for (int r = 0; r < R_; ++r) { offs[r] = acc; acc += lens[r]; }
  }
  __syncthreads();
  for (int i = threadIdx.x; i < R_ * K_; i += 256) {
    int r = i >> 7;
    int k = i & (K_ - 1);
    float v = 0.0f;
    if (k < lens[r]) v = lambdas[offs[r] + k];
    ul[i] = v;
  }
}

// ---------------------------------------------------------------------------
// bbf[r][k][d] = bf16(bases[r][k][d] * ul[r][k])   (scale in fp32, round once)
// ---------------------------------------------------------------------------
__global__ __launch_bounds__(256) void k_cvt_bases(
    const float* __restrict__ bases, const float* __restrict__ ul,
    short* __restrict__ bbf) {
  size_t i = ((size_t)blockIdx.x * 256 + threadIdx.x) * 4;
  if (i >= (size_t)R_ * K_ * D_) return;
  int rk = (int)(i / D_);
  float s = ul[rk];
  float4 v = *(const float4*)(bases + i);
  short4_t o;
  o.x = f2bf(v.x * s); o.y = f2bf(v.y * s);
  o.z = f2bf(v.z * s); o.w = f2bf(v.w * s);
  *(short4_t*)(bbf + i) = o;
}

// ---------------------------------------------------------------------------
// ibt[d][r*K+k] = bf16(invb[r][k][d])   (32x32 LDS-tiled transpose per r)
// ---------------------------------------------------------------------------
__global__ __launch_bounds__(256) void k_trans_inv(
    const float* __restrict__ invb, short* __restrict__ ibt) {
  const int d0 = blockIdx.x * 32;
  const int k0 = blockIdx.y * 32;
  const int r  = blockIdx.z;
  __shared__ short tile[32][33];
  const int t = threadIdx.x;
  {
    int kr = t >> 3;          // 0..31
    int dg = (t & 7) * 4;     // 0..28
    float4 v = *(const float4*)(invb + ((size_t)r * K_ + k0 + kr) * D_ + d0 + dg);
    tile[kr][dg + 0] = f2bf(v.x);
    tile[kr][dg + 1] = f2bf(v.y);
    tile[kr][dg + 2] = f2bf(v.z);
    tile[kr][dg + 3] = f2bf(v.w);
  }
  __syncthreads();
  {
    int dr = t >> 3;          // 0..31
    int kg = (t & 7) * 4;     // 0..28
    short4_t o;
    o.x = tile[kg + 0][dr]; o.y = tile[kg + 1][dr];
    o.z = tile[kg + 2][dr]; o.w = tile[kg + 3][dr];
    *(short4_t*)(ibt + (size_t)(d0 + dr) * (R_ * K_) + r * K_ + k0 + kg) = o;
  }
}

// ---------------------------------------------------------------------------
// out[n,d] = sum over ablated indices of x[n,idx,d]  (initializes out)
// ---------------------------------------------------------------------------
__global__ __launch_bounds__(256) void k_ablated(
    const float* __restrict__ x, const int* __restrict__ abl,
    float* __restrict__ out, int nab) {
  int i = blockIdx.x * 256 + threadIdx.x;
  const int nd4 = N_ * D_ / 4;
  if (i >= nd4) return;
  int n = i / (D_ / 4);
  int d4 = i - n * (D_ / 4);
  const float4* xr = (const float4*)x;
  size_t base = (size_t)n * (S_ * D_ / 4) + d4;
  float4 acc = make_float4(0.f, 0.f, 0.f, 0.f);
  for (int j = 0; j < nab; ++j) {
    float4 v = xr[base + (size_t)abl[j] * (D_ / 4)];
    acc.x += v.x; acc.y += v.y; acc.z += v.z; acc.w += v.w;
  }
  ((float4*)out)[i] = acc;
}

// ---------------------------------------------------------------------------
// Pass 1 (MFMA): per (n-tile 128, r):
//   coeffs[n][r*128+k] = sum_d bf16(x[n,s_r,d]-mu) * bbf[r][k][d]
// 128x128 tile, BK=64, 4 waves, 4x4 mfma_f32_16x16x32_bf16 each.
// A (x - mu, cast) is register-staged into As[128][72] (padded pitch).
// B (bbf)          is async global_load_lds-staged into Bs[128][64] (linear).
// MFMA operand order SWAPPED vs the original (mfma(bf, af, acc)) so the 4
// accumulator regs walk the k dimension -> epilogue packs short4 (8 B) stores.
// ---------------------------------------------------------------------------
__global__ __launch_bounds__(256) void k1_mfma(
    const float* __restrict__ x, const short* __restrict__ bbf,
    const float* __restrict__ means, const int* __restrict__ resi,
    short* __restrict__ coeffs) {
  const int r  = blockIdx.y;
  const int n0 = blockIdx.x * 128;
  const int s  = resi[r];
  const int ldk = R_ * K_;  // 12288

  __shared__ short As[128][72];   // padded: reg-staged
  __shared__ short Bs[128][64];   // linear: global_load_lds

  const int t = threadIdx.x;
  const int wid = t >> 6, l = t & 63;
  const int wr = wid >> 1, wc = wid & 1;
  const int lm = l & 15, quad = l >> 4;

  floatx4 acc[4][4];
#pragma unroll
  for (int i = 0; i < 4; ++i)
#pragma unroll
    for (int j = 0; j < 4; ++j) acc[i][j] = (floatx4)(0.0f);

  const int arow = t >> 4;         // 0..15 (x staging row within round)
  const int acol = (t & 15) * 4;   // 0..60 (floats)

  const float* xb = x + (size_t)s * D_;
  const short* bb = bbf + (size_t)r * K_ * D_;
  const float* mb = means + (size_t)r * D_;

  const int srow = l >> 3;         // 0..7 within an async instr
  const int scol = (l & 7) * 8;    // 0..56 shorts (16 B)

  for (int d0 = 0; d0 < D_; d0 += 64) {
    // B: async global->LDS (4 instrs/wave covers 128 rows x 64 shorts)
#pragma unroll
    for (int ii = 0; ii < 4; ++ii) {
      int rb = wid * 32 + ii * 8;
      stage16(bb + (size_t)(rb + srow) * D_ + d0 + scol, &Bs[rb][0], l);
    }
    // A: register path (subtract mean, cast)
    float4 mv = *(const float4*)(mb + d0 + acol);
#pragma unroll
    for (int rr = 0; rr < 8; ++rr) {
      int row = arow + rr * 16;
      float4 xv = *(const float4*)(xb + (size_t)(n0 + row) * (S_ * D_) + d0 + acol);
      short4_t v;
      v.x = f2bf(xv.x - mv.x); v.y = f2bf(xv.y - mv.y);
      v.z = f2bf(xv.z - mv.z); v.w = f2bf(xv.w - mv.w);
      *(short4_t*)&As[row][acol] = v;
    }
    __syncthreads();   // drains vmcnt (async B) + lgkm (A writes)
#pragma unroll
    for (int kk = 0; kk < 2; ++kk) {
      short8 af[4], bf[4];
#pragma unroll
      for (int i = 0; i < 4; ++i)
        af[i] = *(const short8*)&As[wr * 64 + i * 16 + lm][kk * 32 + quad * 8];
#pragma unroll
      for (int j = 0; j < 4; ++j)
        bf[j] = *(const short8*)&Bs[wc * 64 + j * 16 + lm][kk * 32 + quad * 8];
#pragma unroll
      for (int i = 0; i < 4; ++i)
#pragma unroll
        for (int j = 0; j < 4; ++j)
          acc[i][j] = __builtin_amdgcn_mfma_f32_16x16x32_bf16(
              bf[j], af[i], acc[i][j], 0, 0, 0);   // SWAPPED operands
    }
    __syncthreads();
  }

  // Swapped C/D mapping: row-side <- B tile (k), col-side <- A tile (n):
  //   k = wc*64 + j*16 + quad*4 + g ;  n = n0 + wr*64 + i*16 + lm
  // 4 accumulator regs are 4 consecutive k -> one short4 (8 B) store each.
#pragma unroll
  for (int i = 0; i < 4; ++i) {
    int n = n0 + wr * 64 + i * 16 + lm;
#pragma unroll
    for (int j = 0; j < 4; ++j) {
      int kb = wc * 64 + j * 16 + quad * 4;
      short4_t v;
      v.x = f2bf(acc[i][j][0]); v.y = f2bf(acc[i][j][1]);
      v.z = f2bf(acc[i][j][2]); v.w = f2bf(acc[i][j][3]);
      *(short4_t*)&coeffs[(size_t)n * ldk + r * K_ + kb] = v;
    }
  }
}

// ---------------------------------------------------------------------------
// Pass 2 (MFMA): out(n,d) += coeffs(N x 12288)_bf16 . ibt(768 x 12288)_bf16^T
// m97 structure: both tiles async global_load_lds into linear [128][64] LDS.
// Split-K over blockIdx.z; fp32 atomicAdd epilogue (unchanged, verified).
// ---------------------------------------------------------------------------
static constexpr int SPLITK = 8;
static constexpr int KC = R_ * K_ / SPLITK;  // 1536

__global__ __launch_bounds__(256) void k2_mfma(
    const short* __restrict__ coeffs, const short* __restrict__ ibt,
    float* __restrict__ out) {
  const int n0  = blockIdx.x * 128;
  const int dd0 = blockIdx.y * 128;
  const int kc0 = blockIdx.z * KC;
  const int ldk = R_ * K_;  // 12288

  __shared__ short As[128][64];
  __shared__ short Bs[128][64];

  const int t = threadIdx.x;
  const int wid = t >> 6, l = t & 63;
  const int wr = wid >> 1, wc = wid & 1;
  const int lm = l & 15, quad = l >> 4;

  floatx4 acc[4][4];
#pragma unroll
  for (int i = 0; i < 4; ++i)
#pragma unroll
    for (int j = 0; j < 4; ++j) acc[i][j] = (floatx4)(0.0f);

  const int srow = l >> 3;        // 0..7 within an async instr
  const int scol = (l & 7) * 8;   // 0..56 shorts (16 B)

  for (int k0 = kc0; k0 < kc0 + KC; k0 += 64) {
#pragma unroll
    for (int ii = 0; ii < 4; ++ii) {
      int rb = wid * 32 + ii * 8;
      stage16(coeffs + (size_t)(n0 + rb + srow) * ldk + k0 + scol, &As[rb][0], l);
      stage16(ibt + (size_t)(dd0 + rb + srow) * ldk + k0 + scol, &Bs[rb][0], l);
    }
    __syncthreads();
#pragma unroll
    for (int kk = 0; kk < 2; ++kk) {
      short8 af[4], bf[4];
#pragma unroll
      for (int i = 0; i < 4; ++i)
        af[i] = *(const short8*)&As[wr * 64 + i * 16 + lm][kk * 32 + quad * 8];
#pragma unroll
      for (int j = 0; j < 4; ++j)
        bf[j] = *(const short8*)&Bs[wc * 64 + j * 16 + lm][kk * 32 + quad * 8];
#pragma unroll
      for (int i = 0; i < 4; ++i)
#pragma unroll
        for (int j = 0; j < 4; ++j)
          acc[i][j] = __builtin_amdgcn_mfma_f32_16x16x32_bf16(
              af[i], bf[j], acc[i][j], 0, 0, 0);
    }
    __syncthreads();
  }

  // C/D layout: col = lane&15, row = quad*4 + reg  (verified m89/m91)
#pragma unroll
  for (int i = 0; i < 4; ++i) {
    int row = n0 + wr * 64 + i * 16 + quad * 4;
#pragma unroll
    for (int j = 0; j < 4; ++j) {
      int col = dd0 + wc * 64 + j * 16 + lm;
#pragma unroll
      for (int g = 0; g < 4; ++g)
        atomicAdd(&out[(size_t)(row + g) * D_ + col], acc[i][j][g]);
    }
  }
}

// ===========================================================================
// fp32 fallback path (verified round 2) — used only if ws_size is too small.
// ===========================================================================
__global__ __launch_bounds__(256) void k_pass1(
    const float* __restrict__ x, const float* __restrict__ bases,
    const float* __restrict__ means, const int* __restrict__ resi,
    const float* __restrict__ ul, float* __restrict__ coeffs,
    int r0, int Rc) {
  const int rz = blockIdx.z;
  const int r  = r0 + rz;
  const int n0 = blockIdx.x * 64;
  const int k0 = blockIdx.y * 64;
  const int s  = resi[r];
  __shared__ float As[64][33];
  __shared__ float Bs[64][33];
  const int t  = threadIdx.x;
  const int tx = t & 15, ty = t >> 4;
  const int lc = (t & 7) * 4;
  const int lr = t >> 3;
  const float* xbase = x + (size_t)s * D_;
  const float* bbase = bases + ((size_t)r * K_ + k0) * D_;
  const float* mbase = means + (size_t)r * D_;
  float acc[4][4] = {};
  for (int d0 = 0; d0 < D_; d0 += 32) {
    float4 mv = *(const float4*)(mbase + d0 + lc);
#pragma unroll
    for (int rr = 0; rr < 2; ++rr) {
      int row = lr + rr * 32;
      float4 xv = *(const float4*)(xbase + (size_t)(n0 + row) * (S_ * D_) + d0 + lc);
      As[row][lc + 0] = xv.x - mv.x; As[row][lc + 1] = xv.y - mv.y;
      As[row][lc + 2] = xv.z - mv.z; As[row][lc + 3] = xv.w - mv.w;
      float4 bv = *(const float4*)(bbase + (size_t)row * D_ + d0 + lc);
      Bs[row][lc + 0] = bv.x; Bs[row][lc + 1] = bv.y;
      Bs[row][lc + 2] = bv.z; Bs[row][lc + 3] = bv.w;
    }
    __syncthreads();
#pragma unroll
    for (int dd = 0; dd < 32; ++dd) {
      float a[4], b[4];
#pragma unroll
      for (int i = 0; i < 4; ++i) a[i] = As[ty * 4 + i][dd];
#pragma unroll
      for (int j = 0; j < 4; ++j) b[j] = Bs[tx * 4 + j][dd];
#pragma unroll
      for (int i = 0; i < 4; ++i)
#pragma unroll
        for (int j = 0; j < 4; ++j) acc[i][j] = fmaf(a[i], b[j], acc[i][j]);
    }
    __syncthreads();
  }
  const int ldc = Rc * K_;
#pragma unroll
  for (int i = 0; i < 4; ++i) {
    int n = n0 + ty * 4 + i;
#pragma unroll
    for (int j = 0; j < 4; ++j) {
      int k = k0 + tx * 4 + j;
      coeffs[(size_t)n * ldc + rz * K_ + k] = ul[r * K_ + k] * acc[i][j];
    }
  }
}

__global__ __launch_bounds__(256) void k_pass2(
    const float* __restrict__ coeffs, const float* __restrict__ invb,
    float* __restrict__ out, int Kg) {
  const int n0 = blockIdx.x * 64;
  const int d0 = blockIdx.y * 64;
  __shared__ float As[64][33];
  __shared__ float Bs[32][65];
  const int t  = threadIdx.x;
  const int tx = t & 15, ty = t >> 4;
  const int lca = (t & 7) * 4;
  const int lra = t >> 3;
  const int lcb = (t & 15) * 4;
  const int lrb = t >> 4;
  float acc[4][4] = {};
  for (int kk0 = 0; kk0 < Kg; kk0 += 32) {
#pragma unroll
    for (int rr = 0; rr < 2; ++rr) {
      int row = lra + rr * 32;
      float4 av = *(const float4*)(coeffs + (size_t)(n0 + row) * Kg + kk0 + lca);
      As[row][lca + 0] = av.x; As[row][lca + 1] = av.y;
      As[row][lca + 2] = av.z; As[row][lca + 3] = av.w;
      int brow = lrb + rr * 16;
      float4 bv = *(const float4*)(invb + (size_t)(kk0 + brow) * D_ + d0 + lcb);
      Bs[brow][lcb + 0] = bv.x; Bs[brow][lcb + 1] = bv.y;
      Bs[brow][lcb + 2] = bv.z; Bs[brow][lcb + 3] = bv.w;
    }
    __syncthreads();
#pragma unroll
    for (int kk = 0; kk < 32; ++kk) {
      float a[4], b[4];
#pragma unroll
      for (int i = 0; i < 4; ++i) a[i] = As[ty * 4 + i][kk];
#pragma unroll
      for (int j = 0; j < 4; ++j) b[j] = Bs[kk][tx * 4 + j];
#pragma unroll
      for (int i = 0; i < 4; ++i)
#pragma unroll
        for (int j = 0; j < 4; ++j) acc[i][j] = fmaf(a[i], b[j], acc[i][j]);
    }
    __syncthreads();
  }
#pragma unroll
  for (int i = 0; i < 4; ++i) {
    int n = n0 + ty * 4 + i;
#pragma unroll
    for (int j = 0; j < 4; ++j) {
      int d = d0 + tx * 4 + j;
      out[(size_t)n * D_ + d] += acc[i][j];
    }
  }
}

__global__ __launch_bounds__(256) void k_fused(
    const float* __restrict__ x, const float* __restrict__ bases,
    const float* __restrict__ invb, const float* __restrict__ means,
    const int* __restrict__ resi, const float* __restrict__ lambdas,
    const int* __restrict__ lens, float* __restrict__ out) {
  const int r  = blockIdx.y;
  const int n0 = blockIdx.x * 64;
  const int s  = resi[r];
  __shared__ float As[64][33];
  __shared__ float Bs[128][33];
  __shared__ float Cs[64][132];
  __shared__ float lam[K_];
  __shared__ int offS;
  const int t  = threadIdx.x;
  if (t == 0) {
    int o = 0;
    for (int i = 0; i < r; ++i) o += lens[i];
    offS = o;
  }
  __syncthreads();
  if (t < K_) lam[t] = (t < lens[r]) ? lambdas[offS + t] : 0.0f;
  const int lc = (t & 7) * 4;
  const int lr = t >> 3;
  const float* mbase = means + (size_t)r * D_;
  const float* bbase = bases + (size_t)r * K_ * D_;
  const int tx = t & 15, ty = t >> 4;
  float acc[4][8] = {};
  for (int d0 = 0; d0 < D_; d0 += 32) {
    float4 mv = *(const float4*)(mbase + d0 + lc);
#pragma unroll
    for (int rr = 0; rr < 2; ++rr) {
      int row = lr + rr * 32;
      float4 xv = *(const float4*)(x + ((size_t)(n0 + row) * S_ + s) * D_ + d0 + lc);
      As[row][lc + 0] = xv.x - mv.x; As[row][lc + 1] = xv.y - mv.y;
      As[row][lc + 2] = xv.z - mv.z; As[row][lc + 3] = xv.w - mv.w;
    }
#pragma unroll
    for (int rr = 0; rr < 4; ++rr) {
      int row = lr + rr * 32;
      float4 bv = *(const float4*)(bbase + (size_t)row * D_ + d0 + lc);
      Bs[row][lc + 0] = bv.x; Bs[row][lc + 1] = bv.y;
      Bs[row][lc + 2] = bv.z; Bs[row][lc + 3] = bv.w;
    }
    __syncthreads();
#pragma unroll
    for (int dd = 0; dd < 32; ++dd) {
      float a[4], b[8];
#pragma unroll
      for (int i = 0; i < 4; ++i) a[i] = As[ty * 4 + i][dd];
#pragma unroll
      for (int j = 0; j < 8; ++j) b[j] = Bs[tx * 8 + j][dd];
#pragma unroll
      for (int i = 0; i < 4; ++i)
#pragma unroll
        for (int j = 0; j < 8; ++j) acc[i][j] = fmaf(a[i], b[j], acc[i][j]);
    }
    __syncthreads();
  }
#pragma unroll
  for (int i = 0; i < 4; ++i)
#pragma unroll
    for (int j = 0; j < 8; ++j)
      Cs[ty * 4 + i][tx * 8 + j] = lam[tx * 8 + j] * acc[i][j];
  __syncthreads();
  const float* ibase = invb + (size_t)r * K_ * D_;
  const int tx2 = t & 15;
  for (int d0 = 0; d0 < D_; d0 += 32) {
#pragma unroll
    for (int rr = 0; rr < 4; ++rr) {
      int row = lr + rr * 32;
      float4 bv = *(const float4*)(ibase + (size_t)row * D_ + d0 + lc);
      Bs[row][lc + 0] = bv.x; Bs[row][lc + 1] = bv.y;
      Bs[row][lc + 2] = bv.z; Bs[row][lc + 3] = bv.w;
    }
    __syncthreads();
    float c[4][2] = {};
#pragma unroll
    for (int k = 0; k < K_; ++k) {
      float a[4], b[2];
#pragma unroll
      for (int i = 0; i < 4; ++i) a[i] = Cs[ty * 4 + i][k];
#pragma unroll
      for (int j = 0; j < 2; ++j) b[j] = Bs[k][tx2 * 2 + j];
#pragma unroll
      for (int i = 0; i < 4; ++i)
#pragma unroll
        for (int j = 0; j < 2; ++j) c[i][j] = fmaf(a[i], b[j], c[i][j]);
    }
#pragma unroll
    for (int i = 0; i < 4; ++i)
#pragma unroll
      for (int j = 0; j < 2; ++j)
        atomicAdd(&out[(size_t)(n0 + ty * 4 + i) * D_ + d0 + tx2 * 2 + j], c[i][j]);
    __syncthreads();
  }
}

// ---------------------------------------------------------------------------
extern "C" void kernel_launch(void* const* d_in, const int* in_sizes, int n_in,
                              void* d_out, int out_size, void* d_ws, size_t ws_size,
                              hipStream_t stream) {
  const float* x       = (const float*)d_in[0];
  const float* lambdas = (const float*)d_in[1];
  const float* bases   = (const float*)d_in[2];
  const float* invb    = (const float*)d_in[3];
  const float* means   = (const float*)d_in[4];
  const int*   resi    = (const int*)d_in[5];
  const int*   abl     = (const int*)d_in[6];
  const int*   lens    = (const int*)d_in[7];
  float* out = (float*)d_out;
  const int nab = in_sizes[6];

  // ws layout for MFMA path:
  //   ul     (R*K fp32)         48 KB
  //   bbf    (R*K*D bf16)     18.87 MB   bases * lambda
  //   ibt    (D x R*K bf16)   18.87 MB   invb transposed
  //   coeffs (N x R*K bf16)   25.17 MB
  const size_t ul_b  = (size_t)R_ * K_ * sizeof(float);
  const size_t bbf_b = (size_t)R_ * K_ * D_ * sizeof(short);
  const size_t ibt_b = (size_t)D_ * R_ * K_ * sizeof(short);
  const size_t cf_b  = (size_t)N_ * R_ * K_ * sizeof(short);
  const size_t need  = ul_b + bbf_b + ibt_b + cf_b;

  k_ablated<<<(N_ * D_ / 4 + 255) / 256, 256, 0, stream>>>(x, abl, out, nab);

  if (ws_size >= need) {
    float* ul   = (float*)d_ws;
    short* bbf  = (short*)((char*)d_ws + ul_b);
    short* ibt  = (short*)((char*)d_ws + ul_b + bbf_b);
    short* cfs  = (short*)((char*)d_ws + ul_b + bbf_b + ibt_b);

    k_pad_lambdas<<<1, 256, 0, stream>>>(lambdas, lens, ul);
    k_cvt_bases<<<(R_ * K_ * D_ / 4 + 255) / 256, 256, 0, stream>>>(bases, ul, bbf);
    dim3 gt(D_ / 32, K_ / 32, R_);
    k_trans_inv<<<gt, 256, 0, stream>>>(invb, ibt);
    dim3 g1(N_ / 128, R_);
    k1_mfma<<<g1, 256, 0, stream>>>(x, bbf, means, resi, cfs);
    dim3 g2(N_ / 128, D_ / 128, SPLITK);
    k2_mfma<<<g2, 256, 0, stream>>>(cfs, ibt, out);
    return;
  }

  // fp32 fallback
  const size_t per_r = (size_t)N_ * K_ * sizeof(float);
  if (ws_size >= ul_b + per_r) {
    float* ul = (float*)d_ws;
    float* coeffs = (float*)((char*)d_ws + ul_b);
    int Rc = (int)((ws_size - ul_b) / per_r);
    if (Rc > R_) Rc = R_;
    k_pad_lambdas<<<1, 256, 0, stream>>>(lambdas, lens, ul);
    for (int r0 = 0; r0 < R_; r0 += Rc) {
      int rc = (R_ - r0 < Rc) ? (R_ - r0) : Rc;
      dim3 g1(N_ / 64, K_ / 64, rc);
      k_pass1<<<g1, 256, 0, stream>>>(x, bases, means, resi, ul, coeffs, r0, rc);
      dim3 g2(N_ / 64, D_ / 64);
      k_pass2<<<g2, 256, 0, stream>>>(coeffs, invb + (size_t)r0 * K_ * D_, out,
                                      rc * K_);
    }
  } else {
    dim3 g(N_ / 64, R_);
    k_fused<<<g, 256, 0, stream>>>(x, bases, invb, means, resi, lambdas, lens,
                                   out);
  }
}

// Round 2
// 723.309 us; speedup vs baseline: 1.0443x; 1.0443x over previous
//
#include <hip/hip_runtime.h>

// Problem constants (fixed by the reference).
static constexpr int N_ = 1024;
static constexpr int S_ = 144;
static constexpr int R_ = 96;
static constexpr int K_ = 128;
static constexpr int D_ = 768;

typedef __attribute__((ext_vector_type(8))) short short8;   // 8 bf16 = 4 VGPR
typedef __attribute__((ext_vector_type(4))) short short4_t; // 4 bf16 = 8 B
typedef __attribute__((ext_vector_type(4))) float floatx4;  // MFMA acc

__device__ inline short f2bf(float f) {  // fp32 -> bf16 RNE
  unsigned u = __builtin_bit_cast(unsigned, f);
  return (short)((u + 0x7FFFu + ((u >> 16) & 1u)) >> 16);
}

// Async global->LDS, 16 B per lane. LDS dest is wave-uniform base; HW adds
// lane*16. Fallback path does the equivalent register round-trip.
#if defined(__has_builtin)
#if __has_builtin(__builtin_amdgcn_global_load_lds)
#define HAS_GLL 1
#endif
#endif
#ifndef HAS_GLL
#define HAS_GLL 0
#endif

__device__ __forceinline__ void stage16(const void* g, void* lds_base, int lane) {
#if HAS_GLL
  __builtin_amdgcn_global_load_lds(
      (const __attribute__((address_space(1))) void*)g,
      (__attribute__((address_space(3))) void*)lds_base, 16, 0, 0);
#else
  *(short8*)((short*)lds_base + lane * 8) = *(const short8*)g;
#endif
}

// ---------------------------------------------------------------------------
// Merged prep kernel (all blocks independent):
//   [0, 9216)        : bbf[r][k][d] = bf16(bases[r][k][d])      (pure cast;
//                      lambda is folded into ibt instead — identical algebra)
//   [9216, 18432)    : ibt[d][r*K+k] = bf16(invb[r][k][d] * lam[r][k])
//   [18432, 19200)   : out[n][d] = sum_{ablated s} x[n][s][d]   (out init)
// ---------------------------------------------------------------------------
static constexpr int CVT_B = R_ * K_ * D_ / 1024;          // 9216
static constexpr int TRN_B = (D_ / 32) * (K_ / 32) * R_;   // 9216
static constexpr int ABL_B = N_ * D_ / 4 / 256;            // 768

__global__ __launch_bounds__(256) void k_prep(
    const float* __restrict__ bases, const float* __restrict__ invb,
    const float* __restrict__ lambdas, const int* __restrict__ lens,
    const float* __restrict__ x, const int* __restrict__ abl,
    short* __restrict__ bbf, short* __restrict__ ibt,
    float* __restrict__ out, int nab) {
  const int id = blockIdx.x;
  const int t = threadIdx.x;

  __shared__ float tile[32][33];
  __shared__ float lam[32];
  __shared__ int off_s;

  if (id < CVT_B) {
    // pure streaming cast bases -> bf16
    size_t i = ((size_t)id * 256 + t) * 4;
    float4 v = *(const float4*)(bases + i);
    short4_t o;
    o.x = f2bf(v.x); o.y = f2bf(v.y); o.z = f2bf(v.z); o.w = f2bf(v.w);
    *(short4_t*)(bbf + i) = o;
  } else if (id < CVT_B + TRN_B) {
    // transpose invb per r with lambda scaling folded in
    int b = id - CVT_B;
    const int d0 = (b % 24) * 32;
    const int k0 = ((b / 24) & 3) * 32;
    const int r  = b / 96;
    if (t == 0) {
      int o = 0;
      for (int i = 0; i < r; ++i) o += lens[i];
      off_s = o;
    }
    __syncthreads();
    if (t < 32) {
      int k = k0 + t;
      lam[t] = (k < lens[r]) ? lambdas[off_s + k] : 0.0f;
    }
    {
      int kr = t >> 3;          // 0..31
      int dg = (t & 7) * 4;     // 0..28
      float4 v = *(const float4*)(invb + ((size_t)r * K_ + k0 + kr) * D_ + d0 + dg);
      tile[kr][dg + 0] = v.x; tile[kr][dg + 1] = v.y;
      tile[kr][dg + 2] = v.z; tile[kr][dg + 3] = v.w;
    }
    __syncthreads();
    {
      int dr = t >> 3;          // 0..31
      int kg = (t & 7) * 4;     // 0..28
      short4_t o;
      o.x = f2bf(tile[kg + 0][dr] * lam[kg + 0]);
      o.y = f2bf(tile[kg + 1][dr] * lam[kg + 1]);
      o.z = f2bf(tile[kg + 2][dr] * lam[kg + 2]);
      o.w = f2bf(tile[kg + 3][dr] * lam[kg + 3]);
      *(short4_t*)(ibt + (size_t)(d0 + dr) * (R_ * K_) + r * K_ + k0 + kg) = o;
    }
  } else {
    // ablated sum -> out init
    int i = (id - CVT_B - TRN_B) * 256 + t;
    int n = i / (D_ / 4);
    int d4 = i - n * (D_ / 4);
    const float4* xr = (const float4*)x;
    size_t base = (size_t)n * (S_ * D_ / 4) + d4;
    float4 acc = make_float4(0.f, 0.f, 0.f, 0.f);
    for (int j = 0; j < nab; ++j) {
      float4 v = xr[base + (size_t)abl[j] * (D_ / 4)];
      acc.x += v.x; acc.y += v.y; acc.z += v.z; acc.w += v.w;
    }
    ((float4*)out)[i] = acc;
  }
}

// ---------------------------------------------------------------------------
// Pass 1 (MFMA): per (n-tile 128, r):
//   coeffs[n][r*128+k] = sum_d bf16(x[n,s_r,d]-mu) * bbf[r][k][d]
// (bbf is UNscaled bases; lambda lives in ibt.)
// 128x128 tile, BK=64, 4 waves, 4x4 mfma_f32_16x16x32_bf16 each.
// A (x - mu, cast) reg-staged into As[128][72]; B async-staged (linear).
// MFMA operands swapped so acc regs walk k -> short4 (8 B) packed stores.
// ---------------------------------------------------------------------------
__global__ __launch_bounds__(256) void k1_mfma(
    const float* __restrict__ x, const short* __restrict__ bbf,
    const float* __restrict__ means, const int* __restrict__ resi,
    short* __restrict__ coeffs) {
  const int r  = blockIdx.y;
  const int n0 = blockIdx.x * 128;
  const int s  = resi[r];
  const int ldk = R_ * K_;  // 12288

  __shared__ short As[128][72];   // padded: reg-staged
  __shared__ short Bs[128][64];   // linear: global_load_lds

  const int t = threadIdx.x;
  const int wid = t >> 6, l = t & 63;
  const int wr = wid >> 1, wc = wid & 1;
  const int lm = l & 15, quad = l >> 4;

  floatx4 acc[4][4];
#pragma unroll
  for (int i = 0; i < 4; ++i)
#pragma unroll
    for (int j = 0; j < 4; ++j) acc[i][j] = (floatx4)(0.0f);

  const int arow = t >> 4;         // 0..15 (x staging row within round)
  const int acol = (t & 15) * 4;   // 0..60 (floats)

  const float* xb = x + (size_t)s * D_;
  const short* bb = bbf + (size_t)r * K_ * D_;
  const float* mb = means + (size_t)r * D_;

  const int srow = l >> 3;         // 0..7 within an async instr
  const int scol = (l & 7) * 8;    // 0..56 shorts (16 B)
  (void)srow; (void)scol;

  for (int d0 = 0; d0 < D_; d0 += 64) {
    // B: async global->LDS (4 instrs/wave covers 128 rows x 64 shorts)
#pragma unroll
    for (int ii = 0; ii < 4; ++ii) {
      int rb = wid * 32 + ii * 8;
      stage16(bb + (size_t)(rb + srow) * D_ + d0 + scol, &Bs[rb][0], l);
    }
    // A: register path (subtract mean, cast)
    float4 mv = *(const float4*)(mb + d0 + acol);
#pragma unroll
    for (int rr = 0; rr < 8; ++rr) {
      int row = arow + rr * 16;
      float4 xv = *(const float4*)(xb + (size_t)(n0 + row) * (S_ * D_) + d0 + acol);
      short4_t v;
      v.x = f2bf(xv.x - mv.x); v.y = f2bf(xv.y - mv.y);
      v.z = f2bf(xv.z - mv.z); v.w = f2bf(xv.w - mv.w);
      *(short4_t*)&As[row][acol] = v;
    }
    __syncthreads();   // drains vmcnt (async B) + lgkm (A writes)
#pragma unroll
    for (int kk = 0; kk < 2; ++kk) {
      short8 af[4], bf[4];
#pragma unroll
      for (int i = 0; i < 4; ++i)
        af[i] = *(const short8*)&As[wr * 64 + i * 16 + lm][kk * 32 + quad * 8];
#pragma unroll
      for (int j = 0; j < 4; ++j)
        bf[j] = *(const short8*)&Bs[wc * 64 + j * 16 + lm][kk * 32 + quad * 8];
#pragma unroll
      for (int i = 0; i < 4; ++i)
#pragma unroll
        for (int j = 0; j < 4; ++j)
          acc[i][j] = __builtin_amdgcn_mfma_f32_16x16x32_bf16(
              bf[j], af[i], acc[i][j], 0, 0, 0);   // SWAPPED operands
    }
    __syncthreads();
  }

  // Swapped C/D mapping: k = wc*64 + j*16 + quad*4 + g ; n = n0+wr*64+i*16+lm
#pragma unroll
  for (int i = 0; i < 4; ++i) {
    int n = n0 + wr * 64 + i * 16 + lm;
#pragma unroll
    for (int j = 0; j < 4; ++j) {
      int kb = wc * 64 + j * 16 + quad * 4;
      short4_t v;
      v.x = f2bf(acc[i][j][0]); v.y = f2bf(acc[i][j][1]);
      v.z = f2bf(acc[i][j][2]); v.w = f2bf(acc[i][j][3]);
      *(short4_t*)&coeffs[(size_t)n * ldk + r * K_ + kb] = v;
    }
  }
}

// ---------------------------------------------------------------------------
// Pass 2 (MFMA): out(n,d) += coeffs(N x 12288)_bf16 . ibt(768 x 12288)_bf16^T
// m97 structure: both tiles async global_load_lds into linear [128][64] LDS.
// Split-K over z; fp32 atomicAdd epilogue. 1-D grid with bijective XCD
// swizzle (384 = 8 XCD x 48), d-tile slowest so each XCD's L2 caches one
// 3 MB ibt panel.
// ---------------------------------------------------------------------------
static constexpr int SPLITK = 8;
static constexpr int KC = R_ * K_ / SPLITK;  // 1536

__global__ __launch_bounds__(256) void k2_mfma(
    const short* __restrict__ coeffs, const short* __restrict__ ibt,
    float* __restrict__ out) {
  // bijective XCD swizzle over 384 blocks
  const int id = blockIdx.x;
  const int wg = (id & 7) * 48 + (id >> 3);
  const int bx = wg & 7;          // n-tile   (fastest within XCD chunk)
  const int bz = (wg >> 3) & 7;   // split-k
  const int by = wg >> 6;         // d-tile   (slowest: ibt panel locality)

  const int n0  = bx * 128;
  const int dd0 = by * 128;
  const int kc0 = bz * KC;
  const int ldk = R_ * K_;  // 12288

  __shared__ short As[128][64];
  __shared__ short Bs[128][64];

  const int t = threadIdx.x;
  const int wid = t >> 6, l = t & 63;
  const int wr = wid >> 1, wc = wid & 1;
  const int lm = l & 15, quad = l >> 4;

  floatx4 acc[4][4];
#pragma unroll
  for (int i = 0; i < 4; ++i)
#pragma unroll
    for (int j = 0; j < 4; ++j) acc[i][j] = (floatx4)(0.0f);

  const int srow = l >> 3;        // 0..7 within an async instr
  const int scol = (l & 7) * 8;   // 0..56 shorts (16 B)

  for (int k0 = kc0; k0 < kc0 + KC; k0 += 64) {
#pragma unroll
    for (int ii = 0; ii < 4; ++ii) {
      int rb = wid * 32 + ii * 8;
      stage16(coeffs + (size_t)(n0 + rb + srow) * ldk + k0 + scol, &As[rb][0], l);
      stage16(ibt + (size_t)(dd0 + rb + srow) * ldk + k0 + scol, &Bs[rb][0], l);
    }
    __syncthreads();
#pragma unroll
    for (int kk = 0; kk < 2; ++kk) {
      short8 af[4], bf[4];
#pragma unroll
      for (int i = 0; i < 4; ++i)
        af[i] = *(const short8*)&As[wr * 64 + i * 16 + lm][kk * 32 + quad * 8];
#pragma unroll
      for (int j = 0; j < 4; ++j)
        bf[j] = *(const short8*)&Bs[wc * 64 + j * 16 + lm][kk * 32 + quad * 8];
#pragma unroll
      for (int i = 0; i < 4; ++i)
#pragma unroll
        for (int j = 0; j < 4; ++j)
          acc[i][j] = __builtin_amdgcn_mfma_f32_16x16x32_bf16(
              af[i], bf[j], acc[i][j], 0, 0, 0);
    }
    __syncthreads();
  }

  // C/D layout: col = lane&15, row = quad*4 + reg  (verified m89/m91)
#pragma unroll
  for (int i = 0; i < 4; ++i) {
    int row = n0 + wr * 64 + i * 16 + quad * 4;
#pragma unroll
    for (int j = 0; j < 4; ++j) {
      int col = dd0 + wc * 64 + j * 16 + lm;
#pragma unroll
      for (int g = 0; g < 4; ++g)
        atomicAdd(&out[(size_t)(row + g) * D_ + col], acc[i][j][g]);
    }
  }
}

// ===========================================================================
// fp32 fallback path (verified) — used only if ws_size is too small.
// ===========================================================================
__global__ __launch_bounds__(256) void k_pad_lambdas(
    const float* __restrict__ lambdas, const int* __restrict__ lens,
    float* __restrict__ ul) {
  __shared__ int offs[R_];
  if (threadIdx.x == 0) {
    int acc = 0;
    for (int r = 0; r < R_; ++r) { offs[r] = acc; acc += lens[r]; }
  }
  __syncthreads();
  for (int i = threadIdx.x; i < R_ * K_; i += 256) {
    int r = i >> 7;
    int k = i & (K_ - 1);
    float v = 0.0f;
    if (k < lens[r]) v = lambdas[offs[r] + k];
    ul[i] = v;
  }
}

__global__ __launch_bounds__(256) void k_ablated(
    const float* __restrict__ x, const int* __restrict__ abl,
    float* __restrict__ out, int nab) {
  int i = blockIdx.x * 256 + threadIdx.x;
  const int nd4 = N_ * D_ / 4;
  if (i >= nd4) return;
  int n = i / (D_ / 4);
  int d4 = i - n * (D_ / 4);
  const float4* xr = (const float4*)x;
  size_t base = (size_t)n * (S_ * D_ / 4) + d4;
  float4 acc = make_float4(0.f, 0.f, 0.f, 0.f);
  for (int j = 0; j < nab; ++j) {
    float4 v = xr[base + (size_t)abl[j] * (D_ / 4)];
    acc.x += v.x; acc.y += v.y; acc.z += v.z; acc.w += v.w;
  }
  ((float4*)out)[i] = acc;
}

__global__ __launch_bounds__(256) void k_pass1(
    const float* __restrict__ x, const float* __restrict__ bases,
    const float* __restrict__ means, const int* __restrict__ resi,
    const float* __restrict__ ul, float* __restrict__ coeffs,
    int r0, int Rc) {
  const int rz = blockIdx.z;
  const int r  = r0 + rz;
  const int n0 = blockIdx.x * 64;
  const int k0 = blockIdx.y * 64;
  const int s  = resi[r];
  __shared__ float As[64][33];
  __shared__ float Bs[64][33];
  const int t  = threadIdx.x;
  const int tx = t & 15, ty = t >> 4;
  const int lc = (t & 7) * 4;
  const int lr = t >> 3;
  const float* xbase = x + (size_t)s * D_;
  const float* bbase = bases + ((size_t)r * K_ + k0) * D_;
  const float* mbase = means + (size_t)r * D_;
  float acc[4][4] = {};
  for (int d0 = 0; d0 < D_; d0 += 32) {
    float4 mv = *(const float4*)(mbase + d0 + lc);
#pragma unroll
    for (int rr = 0; rr < 2; ++rr) {
      int row = lr + rr * 32;
      float4 xv = *(const float4*)(xbase + (size_t)(n0 + row) * (S_ * D_) + d0 + lc);
      As[row][lc + 0] = xv.x - mv.x; As[row][lc + 1] = xv.y - mv.y;
      As[row][lc + 2] = xv.z - mv.z; As[row][lc + 3] = xv.w - mv.w;
      float4 bv = *(const float4*)(bbase + (size_t)row * D_ + d0 + lc);
      Bs[row][lc + 0] = bv.x; Bs[row][lc + 1] = bv.y;
      Bs[row][lc + 2] = bv.z; Bs[row][lc + 3] = bv.w;
    }
    __syncthreads();
#pragma unroll
    for (int dd = 0; dd < 32; ++dd) {
      float a[4], b[4];
#pragma unroll
      for (int i = 0; i < 4; ++i) a[i] = As[ty * 4 + i][dd];
#pragma unroll
      for (int j = 0; j < 4; ++j) b[j] = Bs[tx * 4 + j][dd];
#pragma unroll
      for (int i = 0; i < 4; ++i)
#pragma unroll
        for (int j = 0; j < 4; ++j) acc[i][j] = fmaf(a[i], b[j], acc[i][j]);
    }
    __syncthreads();
  }
  const int ldc = Rc * K_;
#pragma unroll
  for (int i = 0; i < 4; ++i) {
    int n = n0 + ty * 4 + i;
#pragma unroll
    for (int j = 0; j < 4; ++j) {
      int k = k0 + tx * 4 + j;
      coeffs[(size_t)n * ldc + rz * K_ + k] = ul[r * K_ + k] * acc[i][j];
    }
  }
}

__global__ __launch_bounds__(256) void k_pass2(
    const float* __restrict__ coeffs, const float* __restrict__ invb,
    float* __restrict__ out, int Kg) {
  const int n0 = blockIdx.x * 64;
  const int d0 = blockIdx.y * 64;
  __shared__ float As[64][33];
  __shared__ float Bs[32][65];
  const int t  = threadIdx.x;
  const int tx = t & 15, ty = t >> 4;
  const int lca = (t & 7) * 4;
  const int lra = t >> 3;
  const int lcb = (t & 15) * 4;
  const int lrb = t >> 4;
  float acc[4][4] = {};
  for (int kk0 = 0; kk0 < Kg; kk0 += 32) {
#pragma unroll
    for (int rr = 0; rr < 2; ++rr) {
      int row = lra + rr * 32;
      float4 av = *(const float4*)(coeffs + (size_t)(n0 + row) * Kg + kk0 + lca);
      As[row][lca + 0] = av.x; As[row][lca + 1] = av.y;
      As[row][lca + 2] = av.z; As[row][lca + 3] = av.w;
      int brow = lrb + rr * 16;
      float4 bv = *(const float4*)(invb + (size_t)(kk0 + brow) * D_ + d0 + lcb);
      Bs[brow][lcb + 0] = bv.x; Bs[brow][lcb + 1] = bv.y;
      Bs[brow][lcb + 2] = bv.z; Bs[brow][lcb + 3] = bv.w;
    }
    __syncthreads();
#pragma unroll
    for (int kk = 0; kk < 32; ++kk) {
      float a[4], b[4];
#pragma unroll
      for (int i = 0; i < 4; ++i) a[i] = As[ty * 4 + i][kk];
#pragma unroll
      for (int j = 0; j < 4; ++j) b[j] = Bs[kk][tx * 4 + j];
#pragma unroll
      for (int i = 0; i < 4; ++i)
#pragma unroll
        for (int j = 0; j < 4; ++j) acc[i][j] = fmaf(a[i], b[j], acc[i][j]);
    }
    __syncthreads();
  }
#pragma unroll
  for (int i = 0; i < 4; ++i) {
    int n = n0 + ty * 4 + i;
#pragma unroll
    for (int j = 0; j < 4; ++j) {
      int d = d0 + tx * 4 + j;
      out[(size_t)n * D_ + d] += acc[i][j];
    }
  }
}

__global__ __launch_bounds__(256) void k_fused(
    const float* __restrict__ x, const float* __restrict__ bases,
    const float* __restrict__ invb, const float* __restrict__ means,
    const int* __restrict__ resi, const float* __restrict__ lambdas,
    const int* __restrict__ lens, float* __restrict__ out) {
  const int r  = blockIdx.y;
  const int n0 = blockIdx.x * 64;
  const int s  = resi[r];
  __shared__ float As[64][33];
  __shared__ float Bs[128][33];
  __shared__ float Cs[64][132];
  __shared__ float lam[K_];
  __shared__ int offS;
  const int t  = threadIdx.x;
  if (t == 0) {
    int o = 0;
    for (int i = 0; i < r; ++i) o += lens[i];
    offS = o;
  }
  __syncthreads();
  if (t < K_) lam[t] = (t < lens[r]) ? lambdas[offS + t] : 0.0f;
  const int lc = (t & 7) * 4;
  const int lr = t >> 3;
  const float* mbase = means + (size_t)r * D_;
  const float* bbase = bases + (size_t)r * K_ * D_;
  const int tx = t & 15, ty = t >> 4;
  float acc[4][8] = {};
  for (int d0 = 0; d0 < D_; d0 += 32) {
    float4 mv = *(const float4*)(mbase + d0 + lc);
#pragma unroll
    for (int rr = 0; rr < 2; ++rr) {
      int row = lr + rr * 32;
      float4 xv = *(const float4*)(x + ((size_t)(n0 + row) * S_ + s) * D_ + d0 + lc);
      As[row][lc + 0] = xv.x - mv.x; As[row][lc + 1] = xv.y - mv.y;
      As[row][lc + 2] = xv.z - mv.z; As[row][lc + 3] = xv.w - mv.w;
    }
#pragma unroll
    for (int rr = 0; rr < 4; ++rr) {
      int row = lr + rr * 32;
      float4 bv = *(const float4*)(bbase + (size_t)row * D_ + d0 + lc);
      Bs[row][lc + 0] = bv.x; Bs[row][lc + 1] = bv.y;
      Bs[row][lc + 2] = bv.z; Bs[row][lc + 3] = bv.w;
    }
    __syncthreads();
#pragma unroll
    for (int dd = 0; dd < 32; ++dd) {
      float a[4], b[8];
#pragma unroll
      for (int i = 0; i < 4; ++i) a[i] = As[ty * 4 + i][dd];
#pragma unroll
      for (int j = 0; j < 8; ++j) b[j] = Bs[tx * 8 + j][dd];
#pragma unroll
      for (int i = 0; i < 4; ++i)
#pragma unroll
        for (int j = 0; j < 8; ++j) acc[i][j] = fmaf(a[i], b[j], acc[i][j]);
    }
    __syncthreads();
  }
#pragma unroll
  for (int i = 0; i < 4; ++i)
#pragma unroll
    for (int j = 0; j < 8; ++j)
      Cs[ty * 4 + i][tx * 8 + j] = lam[tx * 8 + j] * acc[i][j];
  __syncthreads();
  const float* ibase = invb + (size_t)r * K_ * D_;
  const int tx2 = t & 15;
  for (int d0 = 0; d0 < D_; d0 += 32) {
#pragma unroll
    for (int rr = 0; rr < 4; ++rr) {
      int row = lr + rr * 32;
      float4 bv = *(const float4*)(ibase + (size_t)row * D_ + d0 + lc);
      Bs[row][lc + 0] = bv.x; Bs[row][lc + 1] = bv.y;
      Bs[row][lc + 2] = bv.z; Bs[row][lc + 3] = bv.w;
    }
    __syncthreads();
    float c[4][2] = {};
#pragma unroll
    for (int k = 0; k < K_; ++k) {
      float a[4], b[2];
#pragma unroll
      for (int i = 0; i < 4; ++i) a[i] = Cs[ty * 4 + i][k];
#pragma unroll
      for (int j = 0; j < 2; ++j) b[j] = Bs[k][tx2 * 2 + j];
#pragma unroll
      for (int i = 0; i < 4; ++i)
#pragma unroll
        for (int j = 0; j < 2; ++j) c[i][j] = fmaf(a[i], b[j], c[i][j]);
    }
#pragma unroll
    for (int i = 0; i < 4; ++i)
#pragma unroll
      for (int j = 0; j < 2; ++j)
        atomicAdd(&out[(size_t)(n0 + ty * 4 + i) * D_ + d0 + tx2 * 2 + j], c[i][j]);
    __syncthreads();
  }
}

// ---------------------------------------------------------------------------
extern "C" void kernel_launch(void* const* d_in, const int* in_sizes, int n_in,
                              void* d_out, int out_size, void* d_ws, size_t ws_size,
                              hipStream_t stream) {
  const float* x       = (const float*)d_in[0];
  const float* lambdas = (const float*)d_in[1];
  const float* bases   = (const float*)d_in[2];
  const float* invb    = (const float*)d_in[3];
  const float* means   = (const float*)d_in[4];
  const int*   resi    = (const int*)d_in[5];
  const int*   abl     = (const int*)d_in[6];
  const int*   lens    = (const int*)d_in[7];
  float* out = (float*)d_out;
  const int nab = in_sizes[6];

  // ws layout for MFMA path:
  //   bbf    (R*K*D bf16)     18.87 MB   bf16(bases)           [unscaled]
  //   ibt    (D x R*K bf16)   18.87 MB   bf16(invb^T * lambda) [scaled]
  //   coeffs (N x R*K bf16)   25.17 MB
  const size_t bbf_b = (size_t)R_ * K_ * D_ * sizeof(short);
  const size_t ibt_b = (size_t)D_ * R_ * K_ * sizeof(short);
  const size_t cf_b  = (size_t)N_ * R_ * K_ * sizeof(short);
  const size_t need  = bbf_b + ibt_b + cf_b;

  if (ws_size >= need) {
    short* bbf  = (short*)d_ws;
    short* ibt  = (short*)((char*)d_ws + bbf_b);
    short* cfs  = (short*)((char*)d_ws + bbf_b + ibt_b);

    // single merged prep dispatch: cvt + trans(+lambda) + ablated-init
    k_prep<<<CVT_B + TRN_B + ABL_B, 256, 0, stream>>>(
        bases, invb, lambdas, lens, x, abl, bbf, ibt, out, nab);
    dim3 g1(N_ / 128, R_);
    k1_mfma<<<g1, 256, 0, stream>>>(x, bbf, means, resi, cfs);
    k2_mfma<<<(N_ / 128) * (D_ / 128) * SPLITK, 256, 0, stream>>>(cfs, ibt, out);
    return;
  }

  // fp32 fallback
  const size_t ul_b  = (size_t)R_ * K_ * sizeof(float);
  k_ablated<<<(N_ * D_ / 4 + 255) / 256, 256, 0, stream>>>(x, abl, out, nab);
  const size_t per_r = (size_t)N_ * K_ * sizeof(float);
  if (ws_size >= ul_b + per_r) {
    float* ul = (float*)d_ws;
    float* coeffs = (float*)((char*)d_ws + ul_b);
    int Rc = (int)((ws_size - ul_b) / per_r);
    if (Rc > R_) Rc = R_;
    k_pad_lambdas<<<1, 256, 0, stream>>>(lambdas, lens, ul);
    for (int r0 = 0; r0 < R_; r0 += Rc) {
      int rc = (R_ - r0 < Rc) ? (R_ - r0) : Rc;
      dim3 g1(N_ / 64, K_ / 64, rc);
      k_pass1<<<g1, 256, 0, stream>>>(x, bases, means, resi, ul, coeffs, r0, rc);
      dim3 g2(N_ / 64, D_ / 64);
      k_pass2<<<g2, 256, 0, stream>>>(coeffs, invb + (size_t)r0 * K_ * D_, out,
                                      rc * K_);
    }
  } else {
    dim3 g(N_ / 64, R_);
    k_fused<<<g, 256, 0, stream>>>(x, bases, invb, means, resi, lambdas, lens,
                                   out);
  }
}